// Round 1
// baseline (490.265 us; speedup 1.0000x reference)
//
#include <hip/hip_runtime.h>
#include <hip/hip_bf16.h>
#include <type_traits>

typedef _Float16 half8 __attribute__((ext_vector_type(8)));
typedef _Float16 half4 __attribute__((ext_vector_type(4)));
typedef float f32x4 __attribute__((ext_vector_type(4)));

#define MFMA16(A, B, C) __builtin_amdgcn_mfma_f32_16x16x32_f16(A, B, C, 0, 0, 0)

static constexpr int Sdim = 2048;
static constexpr int Hdim = 2048;
static constexpr int NH = 16;
static constexpr int NKV = 8;
static constexpr int HD = 128;
static constexpr float ATT_SCALE = 0.08838834764831845f;  // 1/sqrt(128)

// ---------------- weight transpose + fp16 convert: W[K][N] -> WT[N][K] ----------------
__global__ __launch_bounds__(256) void wtrans(const float* __restrict__ W,
                                              _Float16* __restrict__ WT,
                                              int K, int N) {
  __shared__ __align__(16) float tile[64][68];
  int n0 = blockIdx.x * 64, k0 = blockIdx.y * 64;
  int t = threadIdx.x;
  int c = (t & 15) * 4;
  int rb = t >> 4;
  for (int p = 0; p < 4; ++p) {
    int k = p * 16 + rb;
    *(float4*)&tile[k][c] = *(const float4*)(W + (size_t)(k0 + k) * N + n0 + c);
  }
  __syncthreads();
  int n = t >> 2;
  int kc = (t & 3) * 16;
  half8 o0, o1;
  for (int i = 0; i < 8; ++i) {
    o0[i] = (_Float16)tile[kc + i][n];
    o1[i] = (_Float16)tile[kc + 8 + i][n];
  }
  _Float16* dst = WT + (size_t)(n0 + n) * K + k0 + kc;
  *(half8*)dst = o0;
  *(half8*)(dst + 8) = o1;
}

// ---------------- GEMM: C[M][N] = A[M][Kd] * BT[N][Kd]^T  (fp32 accum, fp16 MFMA) -----
// AT = float (converted during staging) or _Float16. TO=true stores C transposed [N][M].
template <typename AT, typename OT, bool TO>
__global__ __launch_bounds__(256) void gemm_tn(const AT* __restrict__ A,
                                               const _Float16* __restrict__ BT,
                                               OT* __restrict__ C,
                                               int M, int N, int Kd) {
  __shared__ __align__(16) _Float16 As[128][40];
  __shared__ __align__(16) _Float16 Bs[128][40];
  int m0 = blockIdx.y * 128, n0 = blockIdx.x * 128;
  int t = threadIdx.x;
  int lane = t & 63, w = t >> 6;
  int wm = (w & 1) * 64, wn = (w >> 1) * 64;
  int col = lane & 15, quad = lane >> 4;
  f32x4 acc[4][4] = {};
  for (int k0 = 0; k0 < Kd; k0 += 32) {
    if constexpr (std::is_same<AT, float>::value) {
      int r = t >> 3, c = (t & 7) * 4;
      for (int p = 0; p < 4; ++p) {
        float4 v = *(const float4*)(A + (size_t)(m0 + p * 32 + r) * Kd + k0 + c);
        half4 hv = {(_Float16)v.x, (_Float16)v.y, (_Float16)v.z, (_Float16)v.w};
        *(half4*)&As[p * 32 + r][c] = hv;
      }
    } else {
      int r = t >> 2, c = (t & 3) * 8;
      for (int p = 0; p < 2; ++p)
        *(half8*)&As[p * 64 + r][c] =
            *(const half8*)(A + (size_t)(m0 + p * 64 + r) * Kd + k0 + c);
    }
    {
      int r = t >> 2, c = (t & 3) * 8;
      for (int p = 0; p < 2; ++p)
        *(half8*)&Bs[p * 64 + r][c] =
            *(const half8*)(BT + (size_t)(n0 + p * 64 + r) * Kd + k0 + c);
    }
    __syncthreads();
    half8 af[4], bf[4];
    for (int i = 0; i < 4; ++i) af[i] = *(const half8*)&As[wm + i * 16 + col][quad * 8];
    for (int i = 0; i < 4; ++i) bf[i] = *(const half8*)&Bs[wn + i * 16 + col][quad * 8];
    for (int i = 0; i < 4; ++i)
      for (int j = 0; j < 4; ++j)
        acc[i][j] = MFMA16(af[i], bf[j], acc[i][j]);
    __syncthreads();
  }
  for (int i = 0; i < 4; ++i)
    for (int j = 0; j < 4; ++j) {
      if constexpr (TO) {
        int n = n0 + wn + j * 16 + col;
        int mb = m0 + wm + i * 16 + quad * 4;
        half4 hv = {(_Float16)acc[i][j][0], (_Float16)acc[i][j][1],
                    (_Float16)acc[i][j][2], (_Float16)acc[i][j][3]};
        *(half4*)(C + (size_t)n * M + mb) = hv;
      } else {
        for (int r = 0; r < 4; ++r) {
          int m = m0 + wm + i * 16 + quad * 4 + r;
          int n = n0 + wn + j * 16 + col;
          C[(size_t)m * N + n] = (OT)acc[i][j][r];
        }
      }
    }
}

// ---------------- RMSNorm + RoPE: one wave per (token m, head h) ----------------------
__global__ __launch_bounds__(256) void rmsrope(const _Float16* __restrict__ src,
                                               _Float16* __restrict__ dst,
                                               const float* __restrict__ cs,
                                               const float* __restrict__ sn,
                                               const float* __restrict__ nw,
                                               int nh) {
  int w = threadIdx.x >> 6, lane = threadIdx.x & 63;
  int idx = blockIdx.x * 4 + w;
  int m = idx / nh, h = idx - m * nh;
  const _Float16* p = src + (size_t)m * nh * HD + h * HD;
  float x0 = (float)p[lane], x1 = (float)p[lane + 64];
  float ss = x0 * x0 + x1 * x1;
#pragma unroll
  for (int o = 32; o > 0; o >>= 1) ss += __shfl_xor(ss, o);
  float inv = rsqrtf(ss * (1.0f / 128.0f) + 1e-6f);
  float n0v = x0 * inv * nw[lane], n1v = x1 * inv * nw[lane + 64];
  float c0 = cs[m * HD + lane], c1 = cs[m * HD + lane + 64];
  float s0 = sn[m * HD + lane], s1 = sn[m * HD + lane + 64];
  _Float16* q = dst + (size_t)m * nh * HD + h * HD;
  q[lane] = (_Float16)(n0v * c0 - n1v * s0);      // d<64: x*c - x[d+64]*s
  q[lane + 64] = (_Float16)(n1v * c1 + n0v * s1); // d>=64: x*c + x[d-64]*s
}

// ---------------- Flash attention: grid (32 q-blocks, 16 heads), 4 waves --------------
__global__ __launch_bounds__(256) void fattn(const _Float16* __restrict__ Qn,
                                             const _Float16* __restrict__ Kn,
                                             const _Float16* __restrict__ Vt,
                                             _Float16* __restrict__ attn) {
  __shared__ __align__(16) _Float16 Ks[64][136];
  __shared__ __align__(16) _Float16 Vs[128][72];
  __shared__ __align__(16) _Float16 Ps[4][16][72];
  int qb = blockIdx.x, h = blockIdx.y, g = h >> 1;  // GQA: kv head = h/2
  int t = threadIdx.x, lane = t & 63, w = t >> 6;
  int col = lane & 15, quad = lane >> 4;
  half8 qf[4];
  {
    int qrow = qb * 64 + w * 16 + col;
    for (int kc = 0; kc < 4; ++kc)
      qf[kc] = *(const half8*)(Qn + (size_t)qrow * (NH * HD) + h * HD + kc * 32 + quad * 8);
  }
  f32x4 O[8] = {};
  float mi[4], li[4];
  for (int r = 0; r < 4; ++r) { mi[r] = -1e30f; li[r] = 0.0f; }
  for (int kt = 0; kt <= qb; ++kt) {
    {  // stage K-tile [64][128] and V^T-tile [128][64]
      int r = t >> 4, c = (t & 15) * 8;
      for (int p = 0; p < 4; ++p)
        *(half8*)&Ks[p * 16 + r][c] =
            *(const half8*)(Kn + (size_t)(kt * 64 + p * 16 + r) * (NKV * HD) + g * HD + c);
      int d = t >> 3, c2 = (t & 7) * 8;
      for (int p = 0; p < 4; ++p)
        *(half8*)&Vs[p * 32 + d][c2] =
            *(const half8*)(Vt + (size_t)(g * HD + p * 32 + d) * Sdim + kt * 64 + c2);
    }
    __syncthreads();
    f32x4 Sc[4];
    for (int nt = 0; nt < 4; ++nt) {
      f32x4 a = {};
      for (int kc = 0; kc < 4; ++kc) {
        half8 b = *(const half8*)&Ks[nt * 16 + col][kc * 32 + quad * 8];
        a = MFMA16(qf[kc], b, a);
      }
      Sc[nt] = a;
    }
    bool diag = (kt == qb);
    for (int nt = 0; nt < 4; ++nt)
      for (int r = 0; r < 4; ++r) {
        float v = Sc[nt][r] * ATT_SCALE;
        if (diag && (kt * 64 + nt * 16 + col) > (qb * 64 + w * 16 + quad * 4 + r))
          v = -1e30f;
        Sc[nt][r] = v;
      }
    float al[4];
    for (int r = 0; r < 4; ++r) {
      float mx = fmaxf(fmaxf(Sc[0][r], Sc[1][r]), fmaxf(Sc[2][r], Sc[3][r]));
      for (int o = 1; o < 16; o <<= 1) mx = fmaxf(mx, __shfl_xor(mx, o));
      float mnew = fmaxf(mi[r], mx);
      float alpha = __expf(mi[r] - mnew);
      float rs = 0.0f;
      for (int nt = 0; nt < 4; ++nt) {
        float pv = __expf(Sc[nt][r] - mnew);
        Sc[nt][r] = pv;
        rs += pv;
      }
      for (int o = 1; o < 16; o <<= 1) rs += __shfl_xor(rs, o);
      li[r] = li[r] * alpha + rs;
      mi[r] = mnew;
      al[r] = alpha;
    }
    for (int nt = 0; nt < 8; ++nt)
      for (int r = 0; r < 4; ++r) O[nt][r] *= al[r];
    // P: C-layout -> LDS -> A-layout for PV
    for (int nt = 0; nt < 4; ++nt)
      for (int r = 0; r < 4; ++r)
        Ps[w][quad * 4 + r][nt * 16 + col] = (_Float16)Sc[nt][r];
    __syncthreads();
    for (int c2 = 0; c2 < 2; ++c2) {
      half8 ap = *(const half8*)&Ps[w][col][c2 * 32 + quad * 8];
      for (int nt = 0; nt < 8; ++nt) {
        half8 bv = *(const half8*)&Vs[nt * 16 + col][c2 * 32 + quad * 8];
        O[nt] = MFMA16(ap, bv, O[nt]);
      }
    }
    __syncthreads();
  }
  for (int nt = 0; nt < 8; ++nt)
    for (int r = 0; r < 4; ++r) {
      int m = qb * 64 + w * 16 + quad * 4 + r;
      int c2 = h * HD + nt * 16 + col;
      attn[(size_t)m * (NH * HD) + c2] = (_Float16)(O[nt][r] / li[r]);
    }
}

extern "C" void kernel_launch(void* const* d_in, const int* in_sizes, int n_in,
                              void* d_out, int out_size, void* d_ws, size_t ws_size,
                              hipStream_t stream) {
  (void)in_sizes; (void)n_in; (void)out_size; (void)ws_size;
  const float* X  = (const float*)d_in[0];
  const float* cs = (const float*)d_in[1];
  const float* sn = (const float*)d_in[2];
  // d_in[3] attention_mask: exactly causal tril -> handled analytically
  const float* wq = (const float*)d_in[4];
  const float* wk = (const float*)d_in[5];
  const float* wv = (const float*)d_in[6];
  const float* wo = (const float*)d_in[7];
  const float* qw = (const float*)d_in[8];
  const float* kw = (const float*)d_in[9];
  char* ws = (char*)d_ws;
  const size_t MB = 1024 * 1024;
  _Float16* wqT  = (_Float16*)(ws + 0 * MB);   // [2048][2048]
  _Float16* wkT  = (_Float16*)(ws + 8 * MB);   // [1024][2048]
  _Float16* wvT  = (_Float16*)(ws + 12 * MB);  // [1024][2048]
  _Float16* woT  = (_Float16*)(ws + 16 * MB);  // [2048][2048]
  _Float16* Qraw = (_Float16*)(ws + 24 * MB);  // [2048][2048]
  _Float16* Kraw = (_Float16*)(ws + 32 * MB);  // [2048][1024]
  _Float16* Vt   = (_Float16*)(ws + 36 * MB);  // [1024][2048]  (V transposed: [g*128+d][m])
  _Float16* Qn   = (_Float16*)(ws + 40 * MB);  // [2048][2048]
  _Float16* Kn   = (_Float16*)(ws + 48 * MB);  // [2048][1024]
  _Float16* attn = (_Float16*)(ws + 52 * MB);  // [2048][2048]
  float* out = (float*)d_out;

  wtrans<<<dim3(2048 / 64, 2048 / 64), 256, 0, stream>>>(wq, wqT, 2048, 2048);
  wtrans<<<dim3(1024 / 64, 2048 / 64), 256, 0, stream>>>(wk, wkT, 2048, 1024);
  wtrans<<<dim3(1024 / 64, 2048 / 64), 256, 0, stream>>>(wv, wvT, 2048, 1024);
  wtrans<<<dim3(2048 / 64, 2048 / 64), 256, 0, stream>>>(wo, woT, 2048, 2048);

  gemm_tn<float, _Float16, false><<<dim3(16, 16), 256, 0, stream>>>(X, wqT, Qraw, 2048, 2048, 2048);
  gemm_tn<float, _Float16, false><<<dim3(8, 16), 256, 0, stream>>>(X, wkT, Kraw, 2048, 1024, 2048);
  gemm_tn<float, _Float16, true ><<<dim3(8, 16), 256, 0, stream>>>(X, wvT, Vt, 2048, 1024, 2048);

  rmsrope<<<2048 * 16 / 4, 256, 0, stream>>>(Qraw, Qn, cs, sn, qw, 16);
  rmsrope<<<2048 * 8 / 4, 256, 0, stream>>>(Kraw, Kn, cs, sn, kw, 8);

  fattn<<<dim3(32, 16), 256, 0, stream>>>(Qn, Kn, Vt, attn);

  gemm_tn<_Float16, float, false><<<dim3(16, 16), 256, 0, stream>>>(attn, woT, out, 2048, 2048, 2048);
}

// Round 2
// 368.653 us; speedup vs baseline: 1.3299x; 1.3299x over previous
//
#include <hip/hip_runtime.h>
#include <hip/hip_bf16.h>
#include <stdint.h>

typedef _Float16 half8 __attribute__((ext_vector_type(8)));
typedef _Float16 half4 __attribute__((ext_vector_type(4)));
typedef float f32x4 __attribute__((ext_vector_type(4)));

#define MFMA16(A, B, C) __builtin_amdgcn_mfma_f32_16x16x32_f16(A, B, C, 0, 0, 0)

static constexpr int Sdim = 2048;
static constexpr int NH = 16;
static constexpr int NKV = 8;
static constexpr int HD = 128;
static constexpr float ATT_SCALE = 0.08838834764831845f;  // 1/sqrt(128)

// async global->LDS, 16B per lane. LDS dest = wave-uniform base + lane*16 (m104/m108).
__device__ __forceinline__ void async_copy16(const _Float16* g, _Float16* l) {
  auto gp = reinterpret_cast<const __attribute__((address_space(1))) uint32_t*>(
      reinterpret_cast<uintptr_t>(g));
  auto lp = reinterpret_cast<__attribute__((address_space(3))) uint32_t*>(
      reinterpret_cast<uintptr_t>(l));
  __builtin_amdgcn_global_load_lds(gp, lp, 16, 0, 0);
}

// ---------------- X fp32 -> fp16 ------------------------------------------------------
__global__ __launch_bounds__(256) void xconv(const float* __restrict__ X,
                                             _Float16* __restrict__ Xh) {
  int i = (blockIdx.x * 256 + threadIdx.x) * 4;
  float4 v = *(const float4*)(X + i);
  half4 h = {(_Float16)v.x, (_Float16)v.y, (_Float16)v.z, (_Float16)v.w};
  *(half4*)(Xh + i) = h;
}

// ---------------- weight transpose + fp16 convert: W[K][N] -> WT[N][K] ----------------
__global__ __launch_bounds__(256) void wtrans(const float* __restrict__ W,
                                              _Float16* __restrict__ WT,
                                              int K, int N) {
  __shared__ __align__(16) float tile[64][68];
  int n0 = blockIdx.x * 64, k0 = blockIdx.y * 64;
  int t = threadIdx.x;
  int c = (t & 15) * 4;
  int rb = t >> 4;
  for (int p = 0; p < 4; ++p) {
    int k = p * 16 + rb;
    *(float4*)&tile[k][c] = *(const float4*)(W + (size_t)(k0 + k) * N + n0 + c);
  }
  __syncthreads();
  int n = t >> 2;
  int kc = (t & 3) * 16;
  half8 o0, o1;
  for (int i = 0; i < 8; ++i) {
    o0[i] = (_Float16)tile[kc + i][n];
    o1[i] = (_Float16)tile[kc + 8 + i][n];
  }
  _Float16* dst = WT + (size_t)(n0 + n) * K + k0 + kc;
  *(half8*)dst = o0;
  *(half8*)(dst + 8) = o1;
}

// ---------------- fused QKV GEMM (m97 pattern): 128x128 tile, async staging -----------
__global__ __launch_bounds__(256) void gemm_qkv(const _Float16* __restrict__ Xh,
                                                const _Float16* __restrict__ wqT,
                                                const _Float16* __restrict__ wkT,
                                                const _Float16* __restrict__ wvT,
                                                _Float16* __restrict__ Q,
                                                _Float16* __restrict__ K,
                                                _Float16* __restrict__ Vt) {
  __shared__ __align__(16) _Float16 As[128 * 32];
  __shared__ __align__(16) _Float16 Bs[128 * 32];
  int bx = blockIdx.x, m0 = blockIdx.y * 128;
  const _Float16* BT;
  _Float16* outp;
  int n0, Nst;
  bool vt;
  if (bx < 16)      { BT = wqT; outp = Q;  n0 = bx * 128;        vt = false; Nst = 2048; }
  else if (bx < 24) { BT = wkT; outp = K;  n0 = (bx - 16) * 128; vt = false; Nst = 1024; }
  else              { BT = wvT; outp = Vt; n0 = (bx - 24) * 128; vt = true;  Nst = 2048; }
  int t = threadIdx.x, lane = t & 63, w = t >> 6;
  int col = lane & 15, quad = lane >> 4;
  int wm = (w & 1) * 64, wn = (w >> 1) * 64;
  f32x4 acc[4][4] = {};
  for (int k0 = 0; k0 < 2048; k0 += 32) {
    for (int ii = 0; ii < 2; ++ii) {
      int i = w * 2 + ii;
      async_copy16(Xh + (size_t)(m0 + i * 16 + (lane >> 2)) * 2048 + k0 + (lane & 3) * 8,
                   As + i * 512);
      async_copy16(BT + (size_t)(n0 + i * 16 + (lane >> 2)) * 2048 + k0 + (lane & 3) * 8,
                   Bs + i * 512);
    }
    __syncthreads();
    half8 af[4], bf[4];
    for (int i = 0; i < 4; ++i) af[i] = *(const half8*)(As + (wm + i * 16 + col) * 32 + quad * 8);
    for (int i = 0; i < 4; ++i) bf[i] = *(const half8*)(Bs + (wn + i * 16 + col) * 32 + quad * 8);
    for (int i = 0; i < 4; ++i)
      for (int j = 0; j < 4; ++j)
        acc[i][j] = MFMA16(af[i], bf[j], acc[i][j]);
    __syncthreads();
  }
  if (!vt) {
    for (int i = 0; i < 4; ++i)
      for (int j = 0; j < 4; ++j)
        for (int r = 0; r < 4; ++r) {
          int m = m0 + wm + i * 16 + quad * 4 + r;
          int n = n0 + wn + j * 16 + col;
          outp[(size_t)m * Nst + n] = (_Float16)acc[i][j][r];
        }
  } else {
    for (int i = 0; i < 4; ++i)
      for (int j = 0; j < 4; ++j) {
        int n = n0 + wn + j * 16 + col;
        int mb = m0 + wm + i * 16 + quad * 4;
        half4 hv = {(_Float16)acc[i][j][0], (_Float16)acc[i][j][1],
                    (_Float16)acc[i][j][2], (_Float16)acc[i][j][3]};
        *(half4*)(outp + (size_t)n * Sdim + mb) = hv;
      }
  }
}

// ---------------- O GEMM: attn[2048x2048] @ woT -> fp32 out ---------------------------
__global__ __launch_bounds__(256) void gemm_o(const _Float16* __restrict__ A,
                                              const _Float16* __restrict__ BT,
                                              float* __restrict__ C) {
  __shared__ __align__(16) _Float16 As[128 * 32];
  __shared__ __align__(16) _Float16 Bs[128 * 32];
  int m0 = blockIdx.y * 128, n0 = blockIdx.x * 128;
  int t = threadIdx.x, lane = t & 63, w = t >> 6;
  int col = lane & 15, quad = lane >> 4;
  int wm = (w & 1) * 64, wn = (w >> 1) * 64;
  f32x4 acc[4][4] = {};
  for (int k0 = 0; k0 < 2048; k0 += 32) {
    for (int ii = 0; ii < 2; ++ii) {
      int i = w * 2 + ii;
      async_copy16(A + (size_t)(m0 + i * 16 + (lane >> 2)) * 2048 + k0 + (lane & 3) * 8,
                   As + i * 512);
      async_copy16(BT + (size_t)(n0 + i * 16 + (lane >> 2)) * 2048 + k0 + (lane & 3) * 8,
                   Bs + i * 512);
    }
    __syncthreads();
    half8 af[4], bf[4];
    for (int i = 0; i < 4; ++i) af[i] = *(const half8*)(As + (wm + i * 16 + col) * 32 + quad * 8);
    for (int i = 0; i < 4; ++i) bf[i] = *(const half8*)(Bs + (wn + i * 16 + col) * 32 + quad * 8);
    for (int i = 0; i < 4; ++i)
      for (int j = 0; j < 4; ++j)
        acc[i][j] = MFMA16(af[i], bf[j], acc[i][j]);
    __syncthreads();
  }
  for (int i = 0; i < 4; ++i)
    for (int j = 0; j < 4; ++j)
      for (int r = 0; r < 4; ++r) {
        int m = m0 + wm + i * 16 + quad * 4 + r;
        int n = n0 + wn + j * 16 + col;
        C[(size_t)m * 2048 + n] = acc[i][j][r];
      }
}

// ---------------- RMSNorm + RoPE (scale folded for Q) ---------------------------------
__global__ __launch_bounds__(256) void rmsrope(const _Float16* __restrict__ src,
                                               _Float16* __restrict__ dst,
                                               const float* __restrict__ cs,
                                               const float* __restrict__ sn,
                                               const float* __restrict__ nw,
                                               int nh, float scale) {
  int w = threadIdx.x >> 6, lane = threadIdx.x & 63;
  int idx = blockIdx.x * 4 + w;
  int m = idx / nh, h = idx - m * nh;
  const _Float16* p = src + (size_t)m * nh * HD + h * HD;
  float x0 = (float)p[lane], x1 = (float)p[lane + 64];
  float ss = x0 * x0 + x1 * x1;
#pragma unroll
  for (int o = 32; o > 0; o >>= 1) ss += __shfl_xor(ss, o);
  float inv = rsqrtf(ss * (1.0f / 128.0f) + 1e-6f);
  float n0v = x0 * inv * nw[lane], n1v = x1 * inv * nw[lane + 64];
  float c0 = cs[m * HD + lane], c1 = cs[m * HD + lane + 64];
  float s0 = sn[m * HD + lane], s1 = sn[m * HD + lane + 64];
  _Float16* q = dst + (size_t)m * nh * HD + h * HD;
  q[lane] = (_Float16)((n0v * c0 - n1v * s0) * scale);
  q[lane + 64] = (_Float16)((n1v * c1 + n0v * s1) * scale);
}

// ---------------- Flash attention: grid (32 q-blocks, 16 heads), 4 waves --------------
__global__ __launch_bounds__(256) void fattn(const _Float16* __restrict__ Qn,
                                             const _Float16* __restrict__ Kn,
                                             const _Float16* __restrict__ Vt,
                                             _Float16* __restrict__ attn) {
  __shared__ __align__(16) _Float16 Ks[64 * 128];   // [kv][d] unpadded (async staging)
  __shared__ __align__(16) _Float16 Vs[128 * 64];   // [d][kv] unpadded
  __shared__ __align__(16) _Float16 Ps[4][16][80];  // per-wave P transpose buffer
  int qb = blockIdx.x, h = blockIdx.y, g = h >> 1;  // GQA kv head = h/2
  int t = threadIdx.x, lane = t & 63, w = t >> 6;
  int col = lane & 15, quad = lane >> 4;
  half8 qf[4];
  {
    int qrow = qb * 64 + w * 16 + col;
    for (int kc = 0; kc < 4; ++kc)
      qf[kc] = *(const half8*)(Qn + (size_t)qrow * (NH * HD) + h * HD + kc * 32 + quad * 8);
  }
  f32x4 O[8] = {};
  float mi[4], li[4];
  for (int r = 0; r < 4; ++r) { mi[r] = -1e30f; li[r] = 0.0f; }
  for (int kt = 0; kt <= qb; ++kt) {
    // async stage K tile (16 x 1KB) and V^T tile (16 x 1KB); wave w issues i=4w..4w+3
    for (int ii = 0; ii < 4; ++ii) {
      int i = w * 4 + ii;
      async_copy16(Kn + (size_t)(kt * 64 + i * 4 + (lane >> 4)) * (NKV * HD) + g * HD + (lane & 15) * 8,
                   Ks + i * 512);
      async_copy16(Vt + (size_t)(g * HD + i * 8 + (lane >> 3)) * Sdim + kt * 64 + (lane & 7) * 8,
                   Vs + i * 512);
    }
    __syncthreads();
    // S = Qn . K^T  (SCALE pre-folded into Qn)
    f32x4 Sc[4];
    for (int nt = 0; nt < 4; ++nt) {
      f32x4 a = {};
      for (int kc = 0; kc < 4; ++kc) {
        half8 b = *(const half8*)(Ks + (nt * 16 + col) * 128 + kc * 32 + quad * 8);
        a = MFMA16(qf[kc], b, a);
      }
      Sc[nt] = a;
    }
    if (kt == qb) {
      for (int nt = 0; nt < 4; ++nt)
        for (int r = 0; r < 4; ++r)
          if ((nt * 16 + col) > (w * 16 + quad * 4 + r)) Sc[nt][r] = -3e38f;
    }
    // online max; per-lane partial sums (row-sum reduced once in epilogue)
    float al[4];
    for (int r = 0; r < 4; ++r) {
      float mx = fmaxf(fmaxf(Sc[0][r], Sc[1][r]), fmaxf(Sc[2][r], Sc[3][r]));
      mx = fmaxf(mx, __shfl_xor(mx, 1));
      mx = fmaxf(mx, __shfl_xor(mx, 2));
      mx = fmaxf(mx, __shfl_xor(mx, 4));
      mx = fmaxf(mx, __shfl_xor(mx, 8));
      float mnew = fmaxf(mi[r], mx);
      al[r] = __expf(mi[r] - mnew);
      mi[r] = mnew;
      float rs = 0.0f;
      for (int nt = 0; nt < 4; ++nt) {
        float pv = __expf(Sc[nt][r] - mnew);
        Sc[nt][r] = pv;
        rs += pv;
      }
      li[r] = li[r] * al[r] + rs;
    }
    for (int nt = 0; nt < 8; ++nt) {
      f32x4 o = O[nt];
      o[0] *= al[0]; o[1] *= al[1]; o[2] *= al[2]; o[3] *= al[3];
      O[nt] = o;
    }
    // P: C-layout -> per-wave LDS slice -> A-layout (no block barrier needed)
    for (int nt = 0; nt < 4; ++nt)
      for (int r = 0; r < 4; ++r)
        Ps[w][quad * 4 + r][nt * 16 + col] = (_Float16)Sc[nt][r];
    for (int c2 = 0; c2 < 2; ++c2) {
      half8 ap = *(const half8*)&Ps[w][col][c2 * 32 + quad * 8];
      for (int nt = 0; nt < 8; ++nt) {
        half8 bv = *(const half8*)(Vs + (nt * 16 + col) * 64 + c2 * 32 + quad * 8);
        O[nt] = MFMA16(ap, bv, O[nt]);
      }
    }
    __syncthreads();
  }
  for (int r = 0; r < 4; ++r) {
    float s = li[r];
    s += __shfl_xor(s, 1);
    s += __shfl_xor(s, 2);
    s += __shfl_xor(s, 4);
    s += __shfl_xor(s, 8);
    li[r] = 1.0f / s;
  }
  for (int nt = 0; nt < 8; ++nt)
    for (int r = 0; r < 4; ++r) {
      int m = qb * 64 + w * 16 + quad * 4 + r;
      attn[(size_t)m * (NH * HD) + h * HD + nt * 16 + col] = (_Float16)(O[nt][r] * li[r]);
    }
}

extern "C" void kernel_launch(void* const* d_in, const int* in_sizes, int n_in,
                              void* d_out, int out_size, void* d_ws, size_t ws_size,
                              hipStream_t stream) {
  (void)in_sizes; (void)n_in; (void)out_size; (void)ws_size;
  const float* X  = (const float*)d_in[0];
  const float* cs = (const float*)d_in[1];
  const float* sn = (const float*)d_in[2];
  // d_in[3] attention_mask: causal tril -> handled analytically
  const float* wq = (const float*)d_in[4];
  const float* wk = (const float*)d_in[5];
  const float* wv = (const float*)d_in[6];
  const float* wo = (const float*)d_in[7];
  const float* qw = (const float*)d_in[8];
  const float* kw = (const float*)d_in[9];
  char* ws = (char*)d_ws;
  const size_t MB = 1024 * 1024;
  _Float16* wqT  = (_Float16*)(ws + 0 * MB);   // [2048][2048]
  _Float16* wkT  = (_Float16*)(ws + 8 * MB);   // [1024][2048]
  _Float16* wvT  = (_Float16*)(ws + 12 * MB);  // [1024][2048]
  _Float16* woT  = (_Float16*)(ws + 16 * MB);  // [2048][2048]
  _Float16* Xh   = (_Float16*)(ws + 24 * MB);  // [2048][2048]
  _Float16* Qraw = (_Float16*)(ws + 32 * MB);  // [2048][2048]  (reused as attn later)
  _Float16* Kraw = (_Float16*)(ws + 40 * MB);  // [2048][1024]
  _Float16* Vt   = (_Float16*)(ws + 44 * MB);  // [1024][2048]  V^T: [g*128+d][m]
  _Float16* Qn   = (_Float16*)(ws + 48 * MB);  // [2048][2048]
  _Float16* Kn   = (_Float16*)(ws + 56 * MB);  // [2048][1024]
  _Float16* attn = Qraw;                       // Qraw dead after rmsrope
  float* out = (float*)d_out;

  xconv<<<4096, 256, 0, stream>>>(X, Xh);
  wtrans<<<dim3(32, 32), 256, 0, stream>>>(wq, wqT, 2048, 2048);
  wtrans<<<dim3(16, 32), 256, 0, stream>>>(wk, wkT, 2048, 1024);
  wtrans<<<dim3(16, 32), 256, 0, stream>>>(wv, wvT, 2048, 1024);
  wtrans<<<dim3(32, 32), 256, 0, stream>>>(wo, woT, 2048, 2048);

  gemm_qkv<<<dim3(32, 16), 256, 0, stream>>>(Xh, wqT, wkT, wvT, Qraw, Kraw, Vt);

  rmsrope<<<2048 * 16 / 4, 256, 0, stream>>>(Qraw, Qn, cs, sn, qw, 16, ATT_SCALE);
  rmsrope<<<2048 * 8 / 4, 256, 0, stream>>>(Kraw, Kn, cs, sn, kw, 8, 1.0f);

  fattn<<<dim3(32, 16), 256, 0, stream>>>(Qn, Kn, Vt, attn);

  gemm_o<<<dim3(16, 16), 256, 0, stream>>>(attn, woT, out);
}

// Round 3
// 315.901 us; speedup vs baseline: 1.5520x; 1.1670x over previous
//
#include <hip/hip_runtime.h>
#include <hip/hip_bf16.h>
#include <stdint.h>

typedef _Float16 half8 __attribute__((ext_vector_type(8)));
typedef _Float16 half4 __attribute__((ext_vector_type(4)));
typedef float f32x4 __attribute__((ext_vector_type(4)));

#define MFMA16(A, B, C) __builtin_amdgcn_mfma_f32_16x16x32_f16(A, B, C, 0, 0, 0)

static constexpr int Sdim = 2048;
static constexpr int NH = 16;
static constexpr int NKV = 8;
static constexpr int HD = 128;
static constexpr float ATT_SCALE = 0.08838834764831845f;  // 1/sqrt(128)

// async global->LDS, 16B/lane. LDS dest = wave-uniform base + lane*16 (m104/m108).
__device__ __forceinline__ void async_copy16(const _Float16* g, _Float16* l) {
  auto gp = reinterpret_cast<const __attribute__((address_space(1))) uint32_t*>(
      reinterpret_cast<uintptr_t>(g));
  auto lp = reinterpret_cast<__attribute__((address_space(3))) uint32_t*>(
      reinterpret_cast<uintptr_t>(l));
  __builtin_amdgcn_global_load_lds(gp, lp, 16, 0, 0);
}

// ---------------- X fp32 -> fp16 ------------------------------------------------------
__global__ __launch_bounds__(256) void xconv(const float* __restrict__ X,
                                             _Float16* __restrict__ Xh) {
  int i = (blockIdx.x * 256 + threadIdx.x) * 4;
  float4 v = *(const float4*)(X + i);
  half4 h = {(_Float16)v.x, (_Float16)v.y, (_Float16)v.z, (_Float16)v.w};
  *(half4*)(Xh + i) = h;
}

// ---------------- weight transpose + fp16 convert: W[K][N] -> WT[N][K] ----------------
__global__ __launch_bounds__(256) void wtrans(const float* __restrict__ W,
                                              _Float16* __restrict__ WT,
                                              int K, int N) {
  __shared__ __align__(16) float tile[64][68];
  int n0 = blockIdx.x * 64, k0 = blockIdx.y * 64;
  int t = threadIdx.x;
  int c = (t & 15) * 4;
  int rb = t >> 4;
  for (int p = 0; p < 4; ++p) {
    int k = p * 16 + rb;
    *(float4*)&tile[k][c] = *(const float4*)(W + (size_t)(k0 + k) * N + n0 + c);
  }
  __syncthreads();
  int n = t >> 2;
  int kc = (t & 3) * 16;
  half8 o0, o1;
  for (int i = 0; i < 8; ++i) {
    o0[i] = (_Float16)tile[kc + i][n];
    o1[i] = (_Float16)tile[kc + 8 + i][n];
  }
  _Float16* dst = WT + (size_t)(n0 + n) * K + k0 + kc;
  *(half8*)dst = o0;
  *(half8*)(dst + 8) = o1;
}

// 128x32-half tile staging with 4-chunk XOR swizzle: chunk c of row r at c^((r>>1)&3)
__device__ __forceinline__ void stage_gemm_tile(const _Float16* __restrict__ src,
                                                size_t row_stride, int k0,
                                                _Float16* lds, int w, int lane) {
  for (int ii = 0; ii < 2; ++ii) {
    int i = w * 2 + ii;
    int row = i * 16 + (lane >> 2);
    int c = (lane & 3) ^ ((row >> 1) & 3);
    async_copy16(src + (size_t)row * row_stride + k0 + c * 8, lds + i * 512);
  }
}

// ---------------- fused QKV GEMM: 128x128 tile, async staging, swizzled LDS -----------
__global__ __launch_bounds__(256) void gemm_qkv(const _Float16* __restrict__ Xh,
                                                const _Float16* __restrict__ wqT,
                                                const _Float16* __restrict__ wkT,
                                                const _Float16* __restrict__ wvT,
                                                _Float16* __restrict__ Q,
                                                _Float16* __restrict__ K,
                                                _Float16* __restrict__ Vt) {
  __shared__ __align__(16) _Float16 As[128 * 32];
  __shared__ __align__(16) _Float16 Bs[128 * 32];
  int bx = blockIdx.x, m0 = blockIdx.y * 128;
  const _Float16* BT;
  _Float16* outp;
  int n0, Nst;
  bool vt;
  if (bx < 16)      { BT = wqT; outp = Q;  n0 = bx * 128;        vt = false; Nst = 2048; }
  else if (bx < 24) { BT = wkT; outp = K;  n0 = (bx - 16) * 128; vt = false; Nst = 1024; }
  else              { BT = wvT; outp = Vt; n0 = (bx - 24) * 128; vt = true;  Nst = 2048; }
  int t = threadIdx.x, lane = t & 63, w = t >> 6;
  int col = lane & 15, quad = lane >> 4;
  int wm = (w & 1) * 64, wn = (w >> 1) * 64;
  int sw = (quad ^ ((col >> 1) & 3)) * 8;  // swizzled chunk offset (row bits 1-2 = col bits)
  f32x4 acc[4][4] = {};
  for (int k0 = 0; k0 < 2048; k0 += 32) {
    stage_gemm_tile(Xh + (size_t)m0 * 2048, 2048, k0, As, w, lane);
    stage_gemm_tile(BT + (size_t)n0 * 2048, 2048, k0, Bs, w, lane);
    __syncthreads();
    half8 af[4], bf[4];
    for (int i = 0; i < 4; ++i) af[i] = *(const half8*)(As + (wm + i * 16 + col) * 32 + sw);
    for (int i = 0; i < 4; ++i) bf[i] = *(const half8*)(Bs + (wn + i * 16 + col) * 32 + sw);
    for (int i = 0; i < 4; ++i)
      for (int j = 0; j < 4; ++j)
        acc[i][j] = MFMA16(af[i], bf[j], acc[i][j]);
    __syncthreads();
  }
  if (!vt) {
    for (int i = 0; i < 4; ++i)
      for (int j = 0; j < 4; ++j)
        for (int r = 0; r < 4; ++r) {
          int m = m0 + wm + i * 16 + quad * 4 + r;
          int n = n0 + wn + j * 16 + col;
          outp[(size_t)m * Nst + n] = (_Float16)acc[i][j][r];
        }
  } else {
    for (int i = 0; i < 4; ++i)
      for (int j = 0; j < 4; ++j) {
        int n = n0 + wn + j * 16 + col;
        int mb = m0 + wm + i * 16 + quad * 4;
        half4 hv = {(_Float16)acc[i][j][0], (_Float16)acc[i][j][1],
                    (_Float16)acc[i][j][2], (_Float16)acc[i][j][3]};
        *(half4*)(outp + (size_t)n * Sdim + mb) = hv;
      }
  }
}

// ---------------- O GEMM: attn[2048x2048] @ woT -> fp32 out ---------------------------
__global__ __launch_bounds__(256) void gemm_o(const _Float16* __restrict__ A,
                                              const _Float16* __restrict__ BT,
                                              float* __restrict__ C) {
  __shared__ __align__(16) _Float16 As[128 * 32];
  __shared__ __align__(16) _Float16 Bs[128 * 32];
  int m0 = blockIdx.y * 128, n0 = blockIdx.x * 128;
  int t = threadIdx.x, lane = t & 63, w = t >> 6;
  int col = lane & 15, quad = lane >> 4;
  int wm = (w & 1) * 64, wn = (w >> 1) * 64;
  int sw = (quad ^ ((col >> 1) & 3)) * 8;
  f32x4 acc[4][4] = {};
  for (int k0 = 0; k0 < 2048; k0 += 32) {
    stage_gemm_tile(A + (size_t)m0 * 2048, 2048, k0, As, w, lane);
    stage_gemm_tile(BT + (size_t)n0 * 2048, 2048, k0, Bs, w, lane);
    __syncthreads();
    half8 af[4], bf[4];
    for (int i = 0; i < 4; ++i) af[i] = *(const half8*)(As + (wm + i * 16 + col) * 32 + sw);
    for (int i = 0; i < 4; ++i) bf[i] = *(const half8*)(Bs + (wn + i * 16 + col) * 32 + sw);
    for (int i = 0; i < 4; ++i)
      for (int j = 0; j < 4; ++j)
        acc[i][j] = MFMA16(af[i], bf[j], acc[i][j]);
    __syncthreads();
  }
  for (int i = 0; i < 4; ++i)
    for (int j = 0; j < 4; ++j)
      for (int r = 0; r < 4; ++r) {
        int m = m0 + wm + i * 16 + quad * 4 + r;
        int n = n0 + wn + j * 16 + col;
        C[(size_t)m * 2048 + n] = acc[i][j][r];
      }
}

// ---------------- RMSNorm + RoPE (scale folded for Q) ---------------------------------
__global__ __launch_bounds__(256) void rmsrope(const _Float16* __restrict__ src,
                                               _Float16* __restrict__ dst,
                                               const float* __restrict__ cs,
                                               const float* __restrict__ sn,
                                               const float* __restrict__ nw,
                                               int nh, float scale) {
  int w = threadIdx.x >> 6, lane = threadIdx.x & 63;
  int idx = blockIdx.x * 4 + w;
  int m = idx / nh, h = idx - m * nh;
  const _Float16* p = src + (size_t)m * nh * HD + h * HD;
  float x0 = (float)p[lane], x1 = (float)p[lane + 64];
  float ss = x0 * x0 + x1 * x1;
#pragma unroll
  for (int o = 32; o > 0; o >>= 1) ss += __shfl_xor(ss, o);
  float inv = rsqrtf(ss * (1.0f / 128.0f) + 1e-6f);
  float n0v = x0 * inv * nw[lane], n1v = x1 * inv * nw[lane + 64];
  float c0 = cs[m * HD + lane], c1 = cs[m * HD + lane + 64];
  float s0 = sn[m * HD + lane], s1 = sn[m * HD + lane + 64];
  _Float16* q = dst + (size_t)m * nh * HD + h * HD;
  q[lane] = (_Float16)((n0v * c0 - n1v * s0) * scale);
  q[lane + 64] = (_Float16)((n1v * c1 + n0v * s1) * scale);
}

// ---------------- Flash attention: grid (32 q-blocks, 16 heads), 4 waves --------------
// All LDS tiles XOR-chunk-swizzled -> 2-way max bank aliasing (free per m136).
__global__ __launch_bounds__(256) void fattn(const _Float16* __restrict__ Qn,
                                             const _Float16* __restrict__ Kn,
                                             const _Float16* __restrict__ Vt,
                                             _Float16* __restrict__ attn) {
  __shared__ __align__(16) _Float16 Ks[64 * 128];  // [kv][d], chunk c at c^(kv&15)
  __shared__ __align__(16) _Float16 Vs[128 * 64];  // [d][kv], chunk c at c^(d&7)
  __shared__ __align__(16) _Float16 Ps[4 * 1024];  // per-wave [q][kv], chunk c at c^(q&7)
  int qb = (int)gridDim.x - 1 - (int)blockIdx.x;   // heavy blocks dispatch first
  int h = blockIdx.y, g = h >> 1;                  // GQA kv head = h/2
  int t = threadIdx.x, lane = t & 63, w = t >> 6;
  int col = lane & 15, quad = lane >> 4;
  half8 qf[4];
  {
    int qrow = qb * 64 + w * 16 + col;
    for (int kc = 0; kc < 4; ++kc)
      qf[kc] = *(const half8*)(Qn + (size_t)qrow * (NH * HD) + h * HD + kc * 32 + quad * 8);
  }
  _Float16* Psw = Ps + w * 1024;
  f32x4 O[8] = {};
  float mi[4], li[4];
  for (int r = 0; r < 4; ++r) { mi[r] = -1e30f; li[r] = 0.0f; }
  for (int kt = 0; kt <= qb; ++kt) {
    // async stage K tile [64][128] and V^T tile [128][64], swizzled
    for (int ii = 0; ii < 4; ++ii) {
      int i = w * 4 + ii;
      int krow = i * 4 + (lane >> 4);
      int kc = (lane & 15) ^ (krow & 15);
      async_copy16(Kn + (size_t)(kt * 64 + krow) * (NKV * HD) + g * HD + kc * 8,
                   Ks + i * 512);
      int vrow = i * 8 + (lane >> 3);
      int vc = (lane & 7) ^ (vrow & 7);
      async_copy16(Vt + (size_t)(g * HD + vrow) * Sdim + kt * 64 + vc * 8,
                   Vs + i * 512);
    }
    __syncthreads();
    // S = Qn . K^T  (SCALE pre-folded into Qn)
    f32x4 Sc[4];
    for (int nt = 0; nt < 4; ++nt) {
      f32x4 a = {};
      for (int kc = 0; kc < 4; ++kc) {
        half8 b = *(const half8*)(Ks + (nt * 16 + col) * 128 + ((4 * kc + quad) ^ col) * 8);
        a = MFMA16(qf[kc], b, a);
      }
      Sc[nt] = a;
    }
    if (kt == qb) {
      for (int nt = 0; nt < 4; ++nt)
        for (int r = 0; r < 4; ++r)
          if ((nt * 16 + col) > (w * 16 + quad * 4 + r)) Sc[nt][r] = -3e38f;
    }
    // online max; per-lane partial row-sums (reduced once in epilogue)
    float al[4];
    for (int r = 0; r < 4; ++r) {
      float mx = fmaxf(fmaxf(Sc[0][r], Sc[1][r]), fmaxf(Sc[2][r], Sc[3][r]));
      mx = fmaxf(mx, __shfl_xor(mx, 1));
      mx = fmaxf(mx, __shfl_xor(mx, 2));
      mx = fmaxf(mx, __shfl_xor(mx, 4));
      mx = fmaxf(mx, __shfl_xor(mx, 8));
      float mnew = fmaxf(mi[r], mx);
      al[r] = __expf(mi[r] - mnew);
      mi[r] = mnew;
      float rs = 0.0f;
      for (int nt = 0; nt < 4; ++nt) {
        float pv = __expf(Sc[nt][r] - mnew);
        Sc[nt][r] = pv;
        rs += pv;
      }
      li[r] = li[r] * al[r] + rs;
    }
    for (int nt = 0; nt < 8; ++nt) {
      f32x4 o = O[nt];
      o[0] *= al[0]; o[1] *= al[1]; o[2] *= al[2]; o[3] *= al[3];
      O[nt] = o;
    }
    // P: C-layout -> per-wave swizzled LDS slice -> A-layout (no block barrier)
    for (int nt = 0; nt < 4; ++nt)
      for (int r = 0; r < 4; ++r) {
        int q = quad * 4 + r;
        Psw[q * 64 + (((2 * nt + (col >> 3)) ^ (q & 7)) * 8) + (col & 7)] =
            (_Float16)Sc[nt][r];
      }
    for (int c2 = 0; c2 < 2; ++c2) {
      half8 ap = *(const half8*)(Psw + col * 64 + (((4 * c2 + quad) ^ (col & 7)) * 8));
      for (int nt = 0; nt < 8; ++nt) {
        half8 bv = *(const half8*)(Vs + (nt * 16 + col) * 64 +
                                   (((4 * c2 + quad) ^ (col & 7)) * 8));
        O[nt] = MFMA16(ap, bv, O[nt]);
      }
    }
    __syncthreads();
  }
  for (int r = 0; r < 4; ++r) {
    float s = li[r];
    s += __shfl_xor(s, 1);
    s += __shfl_xor(s, 2);
    s += __shfl_xor(s, 4);
    s += __shfl_xor(s, 8);
    li[r] = 1.0f / s;
  }
  for (int nt = 0; nt < 8; ++nt)
    for (int r = 0; r < 4; ++r) {
      int m = qb * 64 + w * 16 + quad * 4 + r;
      attn[(size_t)m * (NH * HD) + h * HD + nt * 16 + col] = (_Float16)(O[nt][r] * li[r]);
    }
}

extern "C" void kernel_launch(void* const* d_in, const int* in_sizes, int n_in,
                              void* d_out, int out_size, void* d_ws, size_t ws_size,
                              hipStream_t stream) {
  (void)in_sizes; (void)n_in; (void)out_size; (void)ws_size;
  const float* X  = (const float*)d_in[0];
  const float* cs = (const float*)d_in[1];
  const float* sn = (const float*)d_in[2];
  // d_in[3] attention_mask: causal tril -> handled analytically
  const float* wq = (const float*)d_in[4];
  const float* wk = (const float*)d_in[5];
  const float* wv = (const float*)d_in[6];
  const float* wo = (const float*)d_in[7];
  const float* qw = (const float*)d_in[8];
  const float* kw = (const float*)d_in[9];
  char* ws = (char*)d_ws;
  const size_t MB = 1024 * 1024;
  _Float16* wqT  = (_Float16*)(ws + 0 * MB);   // [2048][2048]
  _Float16* wkT  = (_Float16*)(ws + 8 * MB);   // [1024][2048]
  _Float16* wvT  = (_Float16*)(ws + 12 * MB);  // [1024][2048]
  _Float16* woT  = (_Float16*)(ws + 16 * MB);  // [2048][2048]
  _Float16* Xh   = (_Float16*)(ws + 24 * MB);  // [2048][2048]
  _Float16* Qraw = (_Float16*)(ws + 32 * MB);  // [2048][2048]  (reused as attn later)
  _Float16* Kraw = (_Float16*)(ws + 40 * MB);  // [2048][1024]
  _Float16* Vt   = (_Float16*)(ws + 44 * MB);  // [1024][2048]  V^T: [g*128+d][m]
  _Float16* Qn   = (_Float16*)(ws + 48 * MB);  // [2048][2048]
  _Float16* Kn   = (_Float16*)(ws + 56 * MB);  // [2048][1024]
  _Float16* attn = Qraw;                       // Qraw dead after rmsrope
  float* out = (float*)d_out;

  xconv<<<4096, 256, 0, stream>>>(X, Xh);
  wtrans<<<dim3(32, 32), 256, 0, stream>>>(wq, wqT, 2048, 2048);
  wtrans<<<dim3(16, 32), 256, 0, stream>>>(wk, wkT, 2048, 1024);
  wtrans<<<dim3(16, 32), 256, 0, stream>>>(wv, wvT, 2048, 1024);
  wtrans<<<dim3(32, 32), 256, 0, stream>>>(wo, woT, 2048, 2048);

  gemm_qkv<<<dim3(32, 16), 256, 0, stream>>>(Xh, wqT, wkT, wvT, Qraw, Kraw, Vt);

  rmsrope<<<2048 * 16 / 4, 256, 0, stream>>>(Qraw, Qn, cs, sn, qw, 16, ATT_SCALE);
  rmsrope<<<2048 * 8 / 4, 256, 0, stream>>>(Kraw, Kn, cs, sn, kw, 8, 1.0f);

  fattn<<<dim3(32, 16), 256, 0, stream>>>(Qn, Kn, Vt, attn);

  gemm_o<<<dim3(16, 16), 256, 0, stream>>>(attn, woT, out);
}

// Round 4
// 284.784 us; speedup vs baseline: 1.7215x; 1.1093x over previous
//
#include <hip/hip_runtime.h>
#include <hip/hip_bf16.h>
#include <stdint.h>

typedef _Float16 half8 __attribute__((ext_vector_type(8)));
typedef _Float16 half4 __attribute__((ext_vector_type(4)));
typedef float f32x4 __attribute__((ext_vector_type(4)));

#define MFMA16(A, B, C) __builtin_amdgcn_mfma_f32_16x16x32_f16(A, B, C, 0, 0, 0)

static constexpr int Sdim = 2048;
static constexpr int NH = 16;
static constexpr int NKV = 8;
static constexpr int HD = 128;
static constexpr float ATT_SCALE = 0.08838834764831845f;  // 1/sqrt(128)
static constexpr float S0 = 4.0f;  // fixed softmax shift: |s| <= 11.32 analytically

// async global->LDS, 16B/lane. LDS dest = wave-uniform base + lane*16 (m104/m108).
__device__ __forceinline__ void async_copy16(const _Float16* g, _Float16* l) {
  auto gp = reinterpret_cast<const __attribute__((address_space(1))) uint32_t*>(
      reinterpret_cast<uintptr_t>(g));
  auto lp = reinterpret_cast<__attribute__((address_space(3))) uint32_t*>(
      reinterpret_cast<uintptr_t>(l));
  __builtin_amdgcn_global_load_lds(gp, lp, 16, 0, 0);
}

// ---------------- X fp32 -> fp16 ------------------------------------------------------
__global__ __launch_bounds__(256) void xconv(const float* __restrict__ X,
                                             _Float16* __restrict__ Xh) {
  int i = (blockIdx.x * 256 + threadIdx.x) * 4;
  float4 v = *(const float4*)(X + i);
  half4 h = {(_Float16)v.x, (_Float16)v.y, (_Float16)v.z, (_Float16)v.w};
  *(half4*)(Xh + i) = h;
}

// ---------------- weight transpose + fp16 convert: W[K][N] -> WT[N][K] ----------------
__global__ __launch_bounds__(256) void wtrans(const float* __restrict__ W,
                                              _Float16* __restrict__ WT,
                                              int K, int N) {
  __shared__ __align__(16) float tile[64][68];
  int n0 = blockIdx.x * 64, k0 = blockIdx.y * 64;
  int t = threadIdx.x;
  int c = (t & 15) * 4;
  int rb = t >> 4;
  for (int p = 0; p < 4; ++p) {
    int k = p * 16 + rb;
    *(float4*)&tile[k][c] = *(const float4*)(W + (size_t)(k0 + k) * N + n0 + c);
  }
  __syncthreads();
  int n = t >> 2;
  int kc = (t & 3) * 16;
  half8 o0, o1;
  for (int i = 0; i < 8; ++i) {
    o0[i] = (_Float16)tile[kc + i][n];
    o1[i] = (_Float16)tile[kc + 8 + i][n];
  }
  _Float16* dst = WT + (size_t)(n0 + n) * K + k0 + kc;
  *(half8*)dst = o0;
  *(half8*)(dst + 8) = o1;
}

// BK=64 tile staging: rows of 64 halves, 8 chunks of 16B, chunk c at c^(row&7).
// NI = instrs per wave (8 rows per instr).
template <int NI>
__device__ __forceinline__ void stage64(const _Float16* __restrict__ src, size_t stride,
                                        int k0, _Float16* lds, int w, int lane) {
  for (int ii = 0; ii < NI; ++ii) {
    int i = w * NI + ii;
    int row = i * 8 + (lane >> 3);
    int c = (lane & 7) ^ (row & 7);
    async_copy16(src + (size_t)row * stride + k0 + c * 8, lds + i * 512);
  }
}

// fragment LDS offset within a BK=64 tile (row&7 == col&7 for all our frag rows)
__device__ __forceinline__ int frag_off(int row, int ks, int quad, int col) {
  return row * 64 + (((ks << 2) | quad) ^ (col & 7)) * 8;
}

// ---------------- fused QKV GEMM: 128x128 tile, BK=64, async swizzled staging ---------
__global__ __launch_bounds__(256) void gemm_qkv(const _Float16* __restrict__ Xh,
                                                const _Float16* __restrict__ wqT,
                                                const _Float16* __restrict__ wkT,
                                                const _Float16* __restrict__ wvT,
                                                _Float16* __restrict__ Q,
                                                _Float16* __restrict__ K,
                                                _Float16* __restrict__ Vt) {
  __shared__ __align__(16) _Float16 As[128 * 64];
  __shared__ __align__(16) _Float16 Bs[128 * 64];
  int bx = blockIdx.x, m0 = blockIdx.y * 128;
  const _Float16* BT;
  _Float16* outp;
  int n0, Nst;
  bool vt;
  if (bx < 16)      { BT = wqT; outp = Q;  n0 = bx * 128;        vt = false; Nst = 2048; }
  else if (bx < 24) { BT = wkT; outp = K;  n0 = (bx - 16) * 128; vt = false; Nst = 1024; }
  else              { BT = wvT; outp = Vt; n0 = (bx - 24) * 128; vt = true;  Nst = 2048; }
  int t = threadIdx.x, lane = t & 63, w = t >> 6;
  int col = lane & 15, quad = lane >> 4;
  int wm = (w & 1) * 64, wn = (w >> 1) * 64;
  f32x4 acc[4][4] = {};
  for (int k0 = 0; k0 < 2048; k0 += 64) {
    stage64<4>(Xh + (size_t)m0 * 2048, 2048, k0, As, w, lane);
    stage64<4>(BT + (size_t)n0 * 2048, 2048, k0, Bs, w, lane);
    __syncthreads();
    half8 af[4][2], bf[4][2];
    for (int i = 0; i < 4; ++i)
      for (int ks = 0; ks < 2; ++ks) {
        af[i][ks] = *(const half8*)(As + frag_off(wm + i * 16 + col, ks, quad, col));
        bf[i][ks] = *(const half8*)(Bs + frag_off(wn + i * 16 + col, ks, quad, col));
      }
    for (int ks = 0; ks < 2; ++ks)
      for (int i = 0; i < 4; ++i)
        for (int j = 0; j < 4; ++j)
          acc[i][j] = MFMA16(af[i][ks], bf[j][ks], acc[i][j]);
    __syncthreads();
  }
  if (!vt) {
    for (int i = 0; i < 4; ++i)
      for (int j = 0; j < 4; ++j)
        for (int r = 0; r < 4; ++r) {
          int m = m0 + wm + i * 16 + quad * 4 + r;
          int n = n0 + wn + j * 16 + col;
          outp[(size_t)m * Nst + n] = (_Float16)acc[i][j][r];
        }
  } else {
    for (int i = 0; i < 4; ++i)
      for (int j = 0; j < 4; ++j) {
        int n = n0 + wn + j * 16 + col;
        int mb = m0 + wm + i * 16 + quad * 4;
        half4 hv = {(_Float16)acc[i][j][0], (_Float16)acc[i][j][1],
                    (_Float16)acc[i][j][2], (_Float16)acc[i][j][3]};
        *(half4*)(outp + (size_t)n * Sdim + mb) = hv;
      }
  }
}

// ---------------- O GEMM: 64x128 tile, BK=64 -> fp32 out ------------------------------
__global__ __launch_bounds__(256) void gemm_o(const _Float16* __restrict__ A,
                                              const _Float16* __restrict__ BT,
                                              float* __restrict__ C) {
  __shared__ __align__(16) _Float16 As[64 * 64];
  __shared__ __align__(16) _Float16 Bs[128 * 64];
  int m0 = blockIdx.y * 64, n0 = blockIdx.x * 128;
  int t = threadIdx.x, lane = t & 63, w = t >> 6;
  int col = lane & 15, quad = lane >> 4;
  int wm = (w & 1) * 32, wn = (w >> 1) * 64;
  f32x4 acc[2][4] = {};
  for (int k0 = 0; k0 < 2048; k0 += 64) {
    stage64<2>(A + (size_t)m0 * 2048, 2048, k0, As, w, lane);
    stage64<4>(BT + (size_t)n0 * 2048, 2048, k0, Bs, w, lane);
    __syncthreads();
    half8 af[2][2], bf[4][2];
    for (int ks = 0; ks < 2; ++ks) {
      for (int i = 0; i < 2; ++i)
        af[i][ks] = *(const half8*)(As + frag_off(wm + i * 16 + col, ks, quad, col));
      for (int j = 0; j < 4; ++j)
        bf[j][ks] = *(const half8*)(Bs + frag_off(wn + j * 16 + col, ks, quad, col));
    }
    for (int ks = 0; ks < 2; ++ks)
      for (int i = 0; i < 2; ++i)
        for (int j = 0; j < 4; ++j)
          acc[i][j] = MFMA16(af[i][ks], bf[j][ks], acc[i][j]);
    __syncthreads();
  }
  for (int i = 0; i < 2; ++i)
    for (int j = 0; j < 4; ++j)
      for (int r = 0; r < 4; ++r) {
        int m = m0 + wm + i * 16 + quad * 4 + r;
        int n = n0 + wn + j * 16 + col;
        C[(size_t)m * 2048 + n] = acc[i][j][r];
      }
}

// ---------------- RMSNorm + RoPE (scale folded for Q) ---------------------------------
__global__ __launch_bounds__(256) void rmsrope(const _Float16* __restrict__ src,
                                               _Float16* __restrict__ dst,
                                               const float* __restrict__ cs,
                                               const float* __restrict__ sn,
                                               const float* __restrict__ nw,
                                               int nh, float scale) {
  int w = threadIdx.x >> 6, lane = threadIdx.x & 63;
  int idx = blockIdx.x * 4 + w;
  int m = idx / nh, h = idx - m * nh;
  const _Float16* p = src + (size_t)m * nh * HD + h * HD;
  float x0 = (float)p[lane], x1 = (float)p[lane + 64];
  float ss = x0 * x0 + x1 * x1;
#pragma unroll
  for (int o = 32; o > 0; o >>= 1) ss += __shfl_xor(ss, o);
  float inv = rsqrtf(ss * (1.0f / 128.0f) + 1e-6f);
  float n0v = x0 * inv * nw[lane], n1v = x1 * inv * nw[lane + 64];
  float c0 = cs[m * HD + lane], c1 = cs[m * HD + lane + 64];
  float s0 = sn[m * HD + lane], s1 = sn[m * HD + lane + 64];
  _Float16* q = dst + (size_t)m * nh * HD + h * HD;
  q[lane] = (_Float16)((n0v * c0 - n1v * s0) * scale);
  q[lane + 64] = (_Float16)((n1v * c1 + n0v * s1) * scale);
}

// ---------------- Flash attention, kv-split x2, fixed-max softmax ---------------------
// grid (32 qb, 16 h, 2 s); block s handles kt = s, s+2, ... <= qb.
// Partials: Op[s][m][h*128+d] fp16 (unnormalized), lp[s][h][m] fp32.
__global__ __launch_bounds__(256) void fattn(const _Float16* __restrict__ Qn,
                                             const _Float16* __restrict__ Kn,
                                             const _Float16* __restrict__ Vt,
                                             _Float16* __restrict__ Op,
                                             float* __restrict__ lp) {
  __shared__ __align__(16) _Float16 Ks[64 * 128];  // [kv][d], chunk c at c^(kv&15)
  __shared__ __align__(16) _Float16 Vs[128 * 64];  // [d][kv], chunk c at c^(d&7)
  __shared__ __align__(16) _Float16 Ps[4 * 1024];  // per-wave [q][kv], chunk c at c^(q&7)
  int qb = (int)gridDim.x - 1 - (int)blockIdx.x;   // heavy blocks dispatch first
  int h = blockIdx.y, g = h >> 1, s = blockIdx.z;  // GQA kv head = h/2
  int t = threadIdx.x, lane = t & 63, w = t >> 6;
  int col = lane & 15, quad = lane >> 4;
  half8 qf[4];
  {
    int qrow = qb * 64 + w * 16 + col;
    for (int kc = 0; kc < 4; ++kc)
      qf[kc] = *(const half8*)(Qn + (size_t)qrow * (NH * HD) + h * HD + kc * 32 + quad * 8);
  }
  _Float16* Psw = Ps + w * 1024;
  f32x4 O[8] = {};
  float li[4] = {0.0f, 0.0f, 0.0f, 0.0f};
  for (int kt = s; kt <= qb; kt += 2) {
    for (int ii = 0; ii < 4; ++ii) {
      int i = w * 4 + ii;
      int krow = i * 4 + (lane >> 4);
      int kc = (lane & 15) ^ (krow & 15);
      async_copy16(Kn + (size_t)(kt * 64 + krow) * (NKV * HD) + g * HD + kc * 8,
                   Ks + i * 512);
      int vrow = i * 8 + (lane >> 3);
      int vc = (lane & 7) ^ (vrow & 7);
      async_copy16(Vt + (size_t)(g * HD + vrow) * Sdim + kt * 64 + vc * 8,
                   Vs + i * 512);
    }
    __syncthreads();
    // S = Qn . K^T (ATT_SCALE pre-folded into Qn)
    f32x4 Sc[4];
    for (int nt = 0; nt < 4; ++nt) {
      f32x4 a = {};
      for (int kc = 0; kc < 4; ++kc) {
        half8 b = *(const half8*)(Ks + (nt * 16 + col) * 128 + ((4 * kc + quad) ^ col) * 8);
        a = MFMA16(qf[kc], b, a);
      }
      Sc[nt] = a;
    }
    if (kt == qb) {
      for (int nt = 0; nt < 4; ++nt)
        for (int r = 0; r < 4; ++r)
          if ((nt * 16 + col) > (w * 16 + quad * 4 + r)) Sc[nt][r] = -1e4f;
    }
    // fixed-max softmax: p = exp(s - S0); no shuffles, no rescale
    for (int nt = 0; nt < 4; ++nt)
      for (int r = 0; r < 4; ++r) {
        float pv = __expf(Sc[nt][r] - S0);
        Sc[nt][r] = pv;
        li[r] += pv;
      }
    // P: C-layout -> per-wave swizzled LDS slice -> A-layout (no block barrier)
    for (int nt = 0; nt < 4; ++nt)
      for (int r = 0; r < 4; ++r) {
        int q = quad * 4 + r;
        Psw[q * 64 + (((2 * nt + (col >> 3)) ^ (q & 7)) * 8) + (col & 7)] =
            (_Float16)Sc[nt][r];
      }
    for (int c2 = 0; c2 < 2; ++c2) {
      half8 ap = *(const half8*)(Psw + col * 64 + (((4 * c2 + quad) ^ (col & 7)) * 8));
      for (int nt = 0; nt < 8; ++nt) {
        half8 bv = *(const half8*)(Vs + (nt * 16 + col) * 64 +
                                   (((4 * c2 + quad) ^ (col & 7)) * 8));
        O[nt] = MFMA16(ap, bv, O[nt]);
      }
    }
    __syncthreads();
  }
  // row-sum reduce across the 16 col-lanes (once, at the end)
  for (int r = 0; r < 4; ++r) {
    float sm = li[r];
    sm += __shfl_xor(sm, 1);
    sm += __shfl_xor(sm, 2);
    sm += __shfl_xor(sm, 4);
    sm += __shfl_xor(sm, 8);
    li[r] = sm;
  }
  _Float16* op = Op + (size_t)s * Sdim * (NH * HD);
  for (int nt = 0; nt < 8; ++nt)
    for (int r = 0; r < 4; ++r) {
      int m = qb * 64 + w * 16 + quad * 4 + r;
      op[(size_t)m * (NH * HD) + h * HD + nt * 16 + col] = (_Float16)O[nt][r];
    }
  if (col == 0) {
    float* lpp = lp + (size_t)s * NH * Sdim + (size_t)h * Sdim;
    for (int r = 0; r < 4; ++r) lpp[qb * 64 + w * 16 + quad * 4 + r] = li[r];
  }
}

// ---------------- merge kv-split partials: attn = (O0+O1)/(l0+l1) ---------------------
__global__ __launch_bounds__(256) void merge(const _Float16* __restrict__ Op,
                                             const float* __restrict__ lp,
                                             _Float16* __restrict__ attn) {
  int m = blockIdx.x, t = threadIdx.x;
  int h = t >> 4, d0 = (t & 15) * 8;
  size_t off = (size_t)m * (NH * HD) + h * HD + d0;
  half8 o0 = *(const half8*)(Op + off);
  half8 o1 = *(const half8*)(Op + (size_t)Sdim * NH * HD + off);
  float l = lp[(size_t)h * Sdim + m] + lp[(size_t)NH * Sdim + (size_t)h * Sdim + m];
  float ri = 1.0f / l;
  half8 o;
  for (int i = 0; i < 8; ++i) o[i] = (_Float16)(((float)o0[i] + (float)o1[i]) * ri);
  *(half8*)(attn + off) = o;
}

extern "C" void kernel_launch(void* const* d_in, const int* in_sizes, int n_in,
                              void* d_out, int out_size, void* d_ws, size_t ws_size,
                              hipStream_t stream) {
  (void)in_sizes; (void)n_in; (void)out_size; (void)ws_size;
  const float* X  = (const float*)d_in[0];
  const float* cs = (const float*)d_in[1];
  const float* sn = (const float*)d_in[2];
  // d_in[3] attention_mask: causal tril -> handled analytically
  const float* wq = (const float*)d_in[4];
  const float* wk = (const float*)d_in[5];
  const float* wv = (const float*)d_in[6];
  const float* wo = (const float*)d_in[7];
  const float* qw = (const float*)d_in[8];
  const float* kw = (const float*)d_in[9];
  char* ws = (char*)d_ws;
  const size_t MB = 1024 * 1024;
  _Float16* wqT  = (_Float16*)(ws + 0 * MB);   // [2048][2048] (dead after gemm_qkv)
  _Float16* wkT  = (_Float16*)(ws + 8 * MB);   // [1024][2048] (dead after gemm_qkv)
  _Float16* wvT  = (_Float16*)(ws + 12 * MB);  // [1024][2048] (dead after gemm_qkv)
  _Float16* woT  = (_Float16*)(ws + 16 * MB);  // [2048][2048] (live until gemm_o)
  _Float16* Xh   = (_Float16*)(ws + 24 * MB);  // [2048][2048]
  _Float16* Qraw = (_Float16*)(ws + 32 * MB);  // [2048][2048] (reused as attn)
  _Float16* Kraw = (_Float16*)(ws + 40 * MB);  // [2048][1024]
  _Float16* Vt   = (_Float16*)(ws + 44 * MB);  // [1024][2048] V^T: [g*128+d][m]
  _Float16* Qn   = (_Float16*)(ws + 48 * MB);  // [2048][2048]
  _Float16* Kn   = (_Float16*)(ws + 56 * MB);  // [2048][1024]
  float*    lp   = (float*)(ws + 60 * MB);     // [2][16][2048]
  _Float16* Op   = wqT;                        // [2][2048][2048] fp16 partials (16MB, over wqT..wvT)
  _Float16* attn = Qraw;
  float* out = (float*)d_out;

  xconv<<<4096, 256, 0, stream>>>(X, Xh);
  wtrans<<<dim3(32, 32), 256, 0, stream>>>(wq, wqT, 2048, 2048);
  wtrans<<<dim3(16, 32), 256, 0, stream>>>(wk, wkT, 2048, 1024);
  wtrans<<<dim3(16, 32), 256, 0, stream>>>(wv, wvT, 2048, 1024);
  wtrans<<<dim3(32, 32), 256, 0, stream>>>(wo, woT, 2048, 2048);

  gemm_qkv<<<dim3(32, 16), 256, 0, stream>>>(Xh, wqT, wkT, wvT, Qraw, Kraw, Vt);

  rmsrope<<<2048 * 16 / 4, 256, 0, stream>>>(Qraw, Qn, cs, sn, qw, 16, ATT_SCALE);
  rmsrope<<<2048 * 8 / 4, 256, 0, stream>>>(Kraw, Kn, cs, sn, kw, 8, 1.0f);

  fattn<<<dim3(32, 16, 2), 256, 0, stream>>>(Qn, Kn, Vt, Op, lp);
  merge<<<2048, 256, 0, stream>>>(Op, lp, attn);

  gemm_o<<<dim3(16, 32), 256, 0, stream>>>(attn, woT, out);
}